// Round 4
// baseline (1835.995 us; speedup 1.0000x reference)
//
#include <hip/hip_runtime.h>
#include <math.h>

typedef unsigned short u16;
typedef unsigned int   u32;

#define LVLS 24
#define CAPN (1 << 18)
#define STR  81           // LDS act row stride in u32 (odd => benign bank pattern)
#define PTS  32           // points per (1-wave) block: LDS 10.4 KB -> 15 waves/CU

typedef float    f32x4 __attribute__((ext_vector_type(4)));
typedef _Float16 f16x8 __attribute__((ext_vector_type(8)));

#if __has_builtin(__builtin_amdgcn_rcpf)
#define RCPF(x) __builtin_amdgcn_rcpf(x)
#else
#define RCPF(x) (1.0f / (x))
#endif
#if __has_builtin(__builtin_amdgcn_exp2f)
#define EXP2F(x) __builtin_amdgcn_exp2f(x)
#else
#define EXP2F(x) exp2f(x)
#endif

// ---- global scaling scheme (fp16-denormal avoidance; verified abs=3.9e-3) ----
// B side (activations / pos / SH / hash feats) stored as 256*x in fp16 hi/lo.
// A side (weights) converted on the fly to 256*w in fp16 hi/lo.
// MFMA acc = 65536 * (x.w); epilogue descales via fmaf(d, 2^-16, bias).
// SELF-CONTAINED: reads ONLY d_in, writes ONLY d_out (no d_ws -> replay-safe).
//
// r4 restructure (latency-bound fix): 32 points / 64-lane wave.
//  - LDS 20992->10496 B: 7 -> 15 waves/CU.
//  - encode: 2 threads/point x 12 levels, unroll 4 -> ~32 gathers in flight.
//  - scalar dots (density, R3): k-split across lane halves + shfl_xor(32).
//  - MFMA: acc[2][4] (2 point-tiles); weight conversion per wave unchanged.

__device__ __forceinline__ float h2f(u16 b) {
    union { u16 u; _Float16 h; } v; v.u = b; return (float)v.h;
}
__device__ __forceinline__ u16 f2h(float x) {
    union { _Float16 h; u16 u; } v; v.h = (_Float16)x; return v.u;   // RNE v_cvt_f16_f32
}
__device__ __forceinline__ void hsplit(float x, u16& h, u16& l) {
    h = f2h(x);
    float r = x - h2f(h);
    l = f2h(r);
}
__device__ __forceinline__ u32 packhl(float x) {
    u16 h, l; hsplit(x, h, l);
    return ((u32)h << 16) | l;
}
__device__ __forceinline__ float unpackhl(u32 w) {
    return h2f((u16)(w >> 16)) + h2f((u16)(w & 0xffffu));
}
// A&S 7.1.26 erf (|eps|<=1.5e-7), hw rcp + exp2
__device__ __forceinline__ float gelu_f(float x) {
    float z  = fabsf(x) * 0.70710678118654752f;
    float t  = RCPF(fmaf(0.3275911f, z, 1.0f));
    float e  = EXP2F(-z * z * 1.44269504088896340f);
    float p  = fmaf(1.061405429f, t, -1.453152027f);
    p = fmaf(p, t, 1.421413741f);
    p = fmaf(p, t, -0.284496736f);
    p = fmaf(p, t, 0.254829592f);
    p = p * t;
    float erfv = fmaf(-p, e, 1.0f);
    float se   = copysignf(erfv, x);
    return x * fmaf(0.5f, se, 0.5f);
}
__device__ __forceinline__ float sigmoid_f(float y) {
    return RCPF(1.0f + EXP2F(-y * 1.44269504088896340f));
}
__device__ __forceinline__ f16x8 cast8h(u32 a, u32 b, u32 c, u32 d) {
    union { u32 u[4]; f16x8 h; } v; v.u[0]=a; v.u[1]=b; v.u[2]=c; v.u[3]=d; return v.h;
}
__device__ __forceinline__ void window_scale(int l, const int* iter, float& sc, float& wl) {
    sc = powf(10.0f, (float)l * (-4.0f / 23.0f));
    double itd = (double)iter[0] / 10000.0;
    itd = itd < 0.0 ? 0.0 : (itd > 1.0 ? 1.0 : itd);
    float tL = (float)((0.3 + 0.7 * itd) * 24.0);
    float arg = fminf(fmaxf(tL - (float)l, 0.0f), 1.0f);
    wl = 0.5f - 0.5f * cosf(3.14159265358979323846f * arg);
}
// 8-corner hash interp for one (point, level) -> f0, f1 (window applied)
__device__ __forceinline__ void hash_level(float px, float py, float pz, float sc, float wl,
                                           int sx, int sy, int sz,
                                           const float* __restrict__ tl,
                                           float& f0, float& f1) {
    float cx = px / sc, cy = py / sc, cz = pz / sc;
    float fx = floorf(cx), fy = floorf(cy), fz = floorf(cz);
    float rx = cx - fx, ry = cy - fy, rz = cz - fz;
    int bx = (int)fx + sx, by = (int)fy + sy, bz = (int)fz + sz;
    u32 hx0 = (u32)bx, hx1 = (u32)(bx + 1);
    u32 hy0 = (u32)by * 2654435761u, hy1 = (u32)(by + 1) * 2654435761u;
    u32 hz0 = (u32)bz * 805459861u,  hz1 = (u32)(bz + 1) * 805459861u;
    float a0 = 0.f, a1 = 0.f;
    #pragma unroll
    for (int c = 0; c < 8; c++) {
        u32 hx = (c & 1) ? hx1 : hx0;
        u32 hy = (c & 2) ? hy1 : hy0;
        u32 hz = (c & 4) ? hz1 : hz0;
        u32 idx = (hx ^ hy ^ hz) & (CAPN - 1);
        float w = ((c & 1) ? rx : 1.0f - rx);
        w *= ((c & 2) ? ry : 1.0f - ry);
        w *= ((c & 4) ? rz : 1.0f - rz);
        float2 tf = *(const float2*)(tl + 2 * (size_t)idx);
        a0 = fmaf(w, tf.x, a0);
        a1 = fmaf(w, tf.y, a1);
    }
    f0 = a0 * wl;
    f1 = a1 * wl;
}

// ============ MFMA layer: weights converted in-register from fp32 d_in ============
// W row-major [Ksrc][ldm], output col m = it*16 + r + coloff.
// D[outfeat][point] for 32 points (jt 0..1).
template <int NKT, bool SHT>
__device__ __forceinline__ void mfma_layer(const float* __restrict__ W, int Ksrc, int ldm, int coloff,
                                           const u32* act, int lane, f32x4 acc[2][4]) {
    const int q = lane >> 4, r = lane & 15;
    #pragma unroll
    for (int jt = 0; jt < 2; jt++)
        #pragma unroll
        for (int it = 0; it < 4; it++)
            acc[jt][it] = (f32x4){0.f, 0.f, 0.f, 0.f};
    #pragma unroll
    for (int kt = 0; kt < NKT; kt++) {
        f16x8 whi[4], wlo[4];
        #pragma unroll
        for (int it = 0; it < 4; it++) {
            const int m  = it * 16 + r + coloff;
            const int k0 = kt * 32 + q * 8;
            #pragma unroll
            for (int e = 0; e < 8; e++) {
                int k = k0 + e;
                float w = (k < Ksrc) ? W[(size_t)k * ldm + m] * 256.0f : 0.0f;
                u16 hh, ll; hsplit(w, hh, ll);
                union { u16 u; _Float16 h; } ch, cl; ch.u = hh; cl.u = ll;
                whi[it][e] = ch.h;
                wlo[it][e] = cl.h;
            }
        }
        #pragma unroll
        for (int jt = 0; jt < 2; jt++) {
            bool zero = SHT && (kt == NKT - 1) && (q >= 2);
            const u32* rowp = act + (jt * 16 + r) * STR + kt * 32 + q * 8;
            u32 v[8];
            #pragma unroll
            for (int e = 0; e < 8; e++) v[e] = zero ? 0u : rowp[e];
            u32 xh[4], xl[4];
            #pragma unroll
            for (int j2 = 0; j2 < 4; j2++) {
                xh[j2] = (v[2*j2] >> 16) | (v[2*j2+1] & 0xffff0000u);
                xl[j2] = (v[2*j2] & 0xffffu) | (v[2*j2+1] << 16);
            }
            f16x8 bh = cast8h(xh[0], xh[1], xh[2], xh[3]);
            f16x8 bl = cast8h(xl[0], xl[1], xl[2], xl[3]);
            #pragma unroll
            for (int it = 0; it < 4; it++) {
                acc[jt][it] = __builtin_amdgcn_mfma_f32_16x16x32_f16(whi[it], bh, acc[jt][it], 0, 0, 0);
                acc[jt][it] = __builtin_amdgcn_mfma_f32_16x16x32_f16(whi[it], bl, acc[jt][it], 0, 0, 0);
                acc[jt][it] = __builtin_amdgcn_mfma_f32_16x16x32_f16(wlo[it], bh, acc[jt][it], 0, 0, 0);
            }
        }
    }
}

__device__ __forceinline__ void epilogue_gelu(f32x4 acc[2][4], const float* __restrict__ bias,
                                              u32* act, int lane) {
    const int q = lane >> 4, r = lane & 15;
    #pragma unroll
    for (int it = 0; it < 4; it++) {
        int mb = it * 16 + q * 4;
        float c0 = bias[mb], c1 = bias[mb + 1], c2 = bias[mb + 2], c3 = bias[mb + 3];
        #pragma unroll
        for (int jt = 0; jt < 2; jt++) {
            f32x4 d = acc[jt][it];
            u32* dst = act + (jt * 16 + r) * STR + mb;
            // descale 2^-16 (A,B both x256), gelu, re-scale 2^8 for the next layer
            dst[0] = packhl(gelu_f(fmaf(d[0], 0x1p-16f, c0)) * 256.0f);
            dst[1] = packhl(gelu_f(fmaf(d[1], 0x1p-16f, c1)) * 256.0f);
            dst[2] = packhl(gelu_f(fmaf(d[2], 0x1p-16f, c2)) * 256.0f);
            dst[3] = packhl(gelu_f(fmaf(d[3], 0x1p-16f, c3)) * 256.0f);
        }
    }
}

// ================= single self-contained kernel: encode + MFMA MLP chain =================
__global__ void __launch_bounds__(64) nerf_all(
    const float* __restrict__ pos, const float* __restrict__ dirs,
    const int* __restrict__ iter, const float* __restrict__ tables,
    const int* __restrict__ shifts,
    const float* __restrict__ W1, const float* __restrict__ b1,
    const float* __restrict__ W2, const float* __restrict__ b2,
    const float* __restrict__ W3, const float* __restrict__ b3,
    const float* __restrict__ W4, const float* __restrict__ b4,
    const float* __restrict__ R1, const float* __restrict__ rb1,
    const float* __restrict__ R2, const float* __restrict__ rb2,
    const float* __restrict__ R3, const float* __restrict__ rb3,
    float* __restrict__ out, int n)
{
    __shared__ u32 act[PTS * STR + 16];   // +16 pad: R1-layer q>=2 predicated reads stay in-bounds
    const int lane = threadIdx.x;         // 0..63
    const int p    = lane & 31;           // point slot (2 threads per point)
    const int h    = lane >> 5;           // half index 0/1
    const int i    = blockIdx.x * PTS + p;
    const bool valid = (i < n);
    u32* myrow = act + p * STR;

    float px = 0.f, py = 0.f, pz = 0.f;
    if (valid) { px = pos[3*i]; py = pos[3*i+1]; pz = pos[3*i+2]; }

    if (h == 0) {
        #pragma unroll
        for (int k = 51; k < 64; k++) myrow[k] = 0u;
        myrow[48] = packhl(px * 256.0f);
        myrow[49] = packhl(py * 256.0f);
        myrow[50] = packhl(pz * 256.0f);
    }

    // encode: this thread does 12 of the 24 levels for its point
    #pragma unroll 4
    for (int li = 0; li < 12; li++) {
        int l = h * 12 + li;
        float sc, wl; window_scale(l, iter, sc, wl);
        float f0, f1;
        hash_level(px, py, pz, sc, wl, shifts[3*l], shifts[3*l+1], shifts[3*l+2],
                   tables + 2 * ((size_t)l * CAPN), f0, f1);
        myrow[2*l]     = (u32)f2h(f0 * 256.0f) << 16;
        myrow[2*l + 1] = (u32)f2h(f1 * 256.0f) << 16;
    }
    __syncthreads();

    f32x4 acc[2][4];
    mfma_layer<2, false>(W1, 51, 64, 0, act, lane, acc);
    epilogue_gelu(acc, b1, act, lane);
    __syncthreads();
    mfma_layer<2, false>(W2, 64, 64, 0, act, lane, acc);
    epilogue_gelu(acc, b2, act, lane);
    __syncthreads();
    mfma_layer<2, false>(W3, 64, 64, 0, act, lane, acc);
    epilogue_gelu(acc, b3, act, lane);
    __syncthreads();

    // density: k-split across lane halves, combine via shfl_xor(32)
    {
        float t = 0.f;
        const int k0 = h * 32;
        #pragma unroll 8
        for (int kk = 0; kk < 32; kk++) {
            float xv = unpackhl(myrow[k0 + kk]);
            t = fmaf(xv, W4[(size_t)(k0 + kk) * 65], t);
        }
        t += __shfl_xor(t, 32);
        float s = fmaf(t, 0x1p-8f, b4[0]);
        if (h == 0 && valid) out[(size_t)3 * n + i] = fmaxf(s, 0.f) + log1pf(expf(-fabsf(s)));
    }
    mfma_layer<2, false>(W4, 64, 65, 1, act, lane, acc);   // W4 cols 1..64
    epilogue_gelu(acc, b4 + 1, act, lane);

    // SH -> feats 64..79 (stored x256); this thread writes its 8 columns
    {
        float dx = 0.f, dy = 0.f, dz = 0.f;
        if (valid) { dx = dirs[3*i]; dy = dirs[3*i+1]; dz = dirs[3*i+2]; }
        float xx = dx*dx, yy = dy*dy, zz = dz*dz;
        float sh[16];
        sh[0]  = 0.28209479177387814f;
        sh[1]  = -0.48860251190291987f * dy;
        sh[2]  = 0.48860251190291987f * dz;
        sh[3]  = -0.48860251190291987f * dx;
        sh[4]  = 1.0925484305920792f * dx * dy;
        sh[5]  = -1.0925484305920792f * dy * dz;
        sh[6]  = 0.94617469575756f * zz - 0.31539156525252f;
        sh[7]  = -1.0925484305920792f * dx * dz;
        sh[8]  = 0.5462742152960396f * (xx - yy);
        sh[9]  = -0.5900435899266435f * dy * (3.0f * xx - yy);
        sh[10] = 2.890611442640554f * dx * dy * dz;
        sh[11] = -0.4570457994644657f * dy * (4.0f * zz - xx - yy);
        sh[12] = 0.37317633259011546f * dz * (2.0f * zz - 3.0f * xx - 3.0f * yy);
        sh[13] = -0.4570457994644657f * dx * (4.0f * zz - xx - yy);
        sh[14] = 1.445305721320277f * dz * (xx - yy);
        sh[15] = -0.5900435899266435f * dx * (xx - 3.0f * yy);
        #pragma unroll
        for (int j = 0; j < 8; j++) myrow[64 + h * 8 + j] = packhl(sh[h * 8 + j] * 256.0f);
    }
    __syncthreads();

    mfma_layer<3, true>(R1, 80, 64, 0, act, lane, acc);
    epilogue_gelu(acc, rb1, act, lane);
    __syncthreads();
    mfma_layer<2, false>(R2, 64, 64, 0, act, lane, acc);
    epilogue_gelu(acc, rb2, act, lane);
    __syncthreads();

    // R3 + sigmoid: k-split across lane halves, combine via shfl_xor(32)
    {
        float t0 = 0.f, t1 = 0.f, t2 = 0.f;
        const int k0 = h * 32;
        #pragma unroll 8
        for (int kk = 0; kk < 32; kk++) {
            float xv = unpackhl(myrow[k0 + kk]);
            t0 = fmaf(xv, R3[(size_t)(k0 + kk) * 3 + 0], t0);
            t1 = fmaf(xv, R3[(size_t)(k0 + kk) * 3 + 1], t1);
            t2 = fmaf(xv, R3[(size_t)(k0 + kk) * 3 + 2], t2);
        }
        t0 += __shfl_xor(t0, 32);
        t1 += __shfl_xor(t1, 32);
        t2 += __shfl_xor(t2, 32);
        if (h == 0 && valid) {
            float y0 = fmaf(t0, 0x1p-8f, rb3[0]);
            float y1 = fmaf(t1, 0x1p-8f, rb3[1]);
            float y2 = fmaf(t2, 0x1p-8f, rb3[2]);
            out[(size_t)3 * i + 0] = sigmoid_f(y0);
            out[(size_t)3 * i + 1] = sigmoid_f(y1);
            out[(size_t)3 * i + 2] = sigmoid_f(y2);
        }
    }
}

extern "C" void kernel_launch(void* const* d_in, const int* in_sizes, int n_in,
                              void* d_out, int out_size, void* d_ws, size_t ws_size,
                              hipStream_t stream) {
    (void)d_ws; (void)ws_size;
    int n = in_sizes[0] / 3;
    int grid = (n + PTS - 1) / PTS;

    nerf_all<<<grid, 64, 0, stream>>>(
        (const float*)d_in[0], (const float*)d_in[1], (const int*)d_in[2],
        (const float*)d_in[3], (const int*)d_in[4],
        (const float*)d_in[5],  (const float*)d_in[6],
        (const float*)d_in[7],  (const float*)d_in[8],
        (const float*)d_in[9],  (const float*)d_in[10],
        (const float*)d_in[11], (const float*)d_in[12],
        (const float*)d_in[13], (const float*)d_in[14],
        (const float*)d_in[15], (const float*)d_in[16],
        (const float*)d_in[17], (const float*)d_in[18],
        (float*)d_out, n);
}

// Round 5
// 1419.370 us; speedup vs baseline: 1.2935x; 1.2935x over previous
//
#include <hip/hip_runtime.h>
#include <math.h>

typedef unsigned short u16;
typedef unsigned int   u32;

#define LVLS 24
#define CAPN (1 << 18)
#define STR  81            // act row stride in u32 (odd => benign bank pattern)
#define WAVES 8            // waves per block (512 threads)
#define TPW  16            // points per wave tile
#define ACTSZ (TPW * STR + 16)   // 1312 u32 per wave act slice (+pad for R1 q>=2 reads)

// ---- LDS layout (u32 offsets) ----
// converted weight blob (hi/lo fp16 pairs), same layout as the old d_ws blob:
#define WB1   0
#define WB2   4096
#define WB3   8192
#define WB4   12288        /* W4 cols 1..64 */
#define WBR1  16384        /* NKT=3 */
#define WBR2  22528        /* blob end 26624 */
#define SWOFF 26624        /* 24 x {scale, window} floats  -> 48 u32 */
#define W4C   26672        /* W4 column 0 (64 floats) */
#define R3C   26736        /* R3 64x3 floats (192) */
#define SHF   26928        /* shifts 24x3 ints (72) */
#define ACT0  27008        /* 8 wave act slices of ACTSZ */
#define LDS_U32 (ACT0 + WAVES * ACTSZ)   /* 37504 u32 = 150016 B <= 160 KiB */

typedef float    f32x4 __attribute__((ext_vector_type(4)));
typedef _Float16 f16x8 __attribute__((ext_vector_type(8)));

#if __has_builtin(__builtin_amdgcn_rcpf)
#define RCPF(x) __builtin_amdgcn_rcpf(x)
#else
#define RCPF(x) (1.0f / (x))
#endif
#if __has_builtin(__builtin_amdgcn_exp2f)
#define EXP2F(x) __builtin_amdgcn_exp2f(x)
#else
#define EXP2F(x) exp2f(x)
#endif

// ---- global scaling scheme (fp16-denormal avoidance; verified abs=3.9e-3) ----
// B side (activations / pos / SH / hash feats) stored as 256*x in fp16 hi/lo.
// A side (weights) converted once per block to 256*w hi/lo blob in LDS.
// MFMA acc = 65536 * (x.w); epilogue descales via fmaf(d, 2^-16, bias).
// SELF-CONTAINED: reads ONLY d_in, writes ONLY d_out (no d_ws -> replay-safe).
//
// r5: persistent blocks. r4 post-mortem showed the dominant cost scales with
// wave count: per-wave fp32 weight re-read (~104KB, L2-thrashed by gathers,
// FETCH +57% when blocks doubled) + hi/lo conversion VALU. Fix: 1 block/CU,
// 8 waves, convert weights ONCE per block into a 104KB LDS blob; each wave
// free-runs over 16-point tiles (intra-wave lgkmcnt fence instead of
// __syncthreads; act slices are wave-private).

__device__ __forceinline__ float h2f(u16 b) {
    union { u16 u; _Float16 h; } v; v.u = b; return (float)v.h;
}
__device__ __forceinline__ u16 f2h(float x) {
    union { _Float16 h; u16 u; } v; v.h = (_Float16)x; return v.u;   // RNE v_cvt_f16_f32
}
__device__ __forceinline__ void hsplit(float x, u16& h, u16& l) {
    h = f2h(x);
    float r = x - h2f(h);
    l = f2h(r);
}
__device__ __forceinline__ u32 packhl(float x) {
    u16 h, l; hsplit(x, h, l);
    return ((u32)h << 16) | l;
}
__device__ __forceinline__ float unpackhl(u32 w) {
    return h2f((u16)(w >> 16)) + h2f((u16)(w & 0xffffu));
}
// A&S 7.1.26 erf (|eps|<=1.5e-7), hw rcp + exp2
__device__ __forceinline__ float gelu_f(float x) {
    float z  = fabsf(x) * 0.70710678118654752f;
    float t  = RCPF(fmaf(0.3275911f, z, 1.0f));
    float e  = EXP2F(-z * z * 1.44269504088896340f);
    float p  = fmaf(1.061405429f, t, -1.453152027f);
    p = fmaf(p, t, 1.421413741f);
    p = fmaf(p, t, -0.284496736f);
    p = fmaf(p, t, 0.254829592f);
    p = p * t;
    float erfv = fmaf(-p, e, 1.0f);
    float se   = copysignf(erfv, x);
    return x * fmaf(0.5f, se, 0.5f);
}
__device__ __forceinline__ float sigmoid_f(float y) {
    return RCPF(1.0f + EXP2F(-y * 1.44269504088896340f));
}
__device__ __forceinline__ f16x8 cast8h(u32 a, u32 b, u32 c, u32 d) {
    union { u32 u[4]; f16x8 h; } v; v.u[0]=a; v.u[1]=b; v.u[2]=c; v.u[3]=d; return v.h;
}
__device__ __forceinline__ void window_scale(int l, const int* iter, float& sc, float& wl) {
    sc = powf(10.0f, (float)l * (-4.0f / 23.0f));
    double itd = (double)iter[0] / 10000.0;
    itd = itd < 0.0 ? 0.0 : (itd > 1.0 ? 1.0 : itd);
    float tL = (float)((0.3 + 0.7 * itd) * 24.0);
    float arg = fminf(fmaxf(tL - (float)l, 0.0f), 1.0f);
    wl = 0.5f - 0.5f * cosf(3.14159265358979323846f * arg);
}
// 8-corner hash interp for one (point, level) -> f0, f1 (window applied)
__device__ __forceinline__ void hash_level(float px, float py, float pz, float sc, float wl,
                                           int sx, int sy, int sz,
                                           const float* __restrict__ tl,
                                           float& f0, float& f1) {
    float cx = px / sc, cy = py / sc, cz = pz / sc;
    float fx = floorf(cx), fy = floorf(cy), fz = floorf(cz);
    float rx = cx - fx, ry = cy - fy, rz = cz - fz;
    int bx = (int)fx + sx, by = (int)fy + sy, bz = (int)fz + sz;
    u32 hx0 = (u32)bx, hx1 = (u32)(bx + 1);
    u32 hy0 = (u32)by * 2654435761u, hy1 = (u32)(by + 1) * 2654435761u;
    u32 hz0 = (u32)bz * 805459861u,  hz1 = (u32)(bz + 1) * 805459861u;
    float a0 = 0.f, a1 = 0.f;
    #pragma unroll
    for (int c = 0; c < 8; c++) {
        u32 hx = (c & 1) ? hx1 : hx0;
        u32 hy = (c & 2) ? hy1 : hy0;
        u32 hz = (c & 4) ? hz1 : hz0;
        u32 idx = (hx ^ hy ^ hz) & (CAPN - 1);
        float w = ((c & 1) ? rx : 1.0f - rx);
        w *= ((c & 2) ? ry : 1.0f - ry);
        w *= ((c & 4) ? rz : 1.0f - rz);
        float2 tf = *(const float2*)(tl + 2 * (size_t)idx);
        a0 = fmaf(w, tf.x, a0);
        a1 = fmaf(w, tf.y, a1);
    }
    f0 = a0 * wl;
    f1 = a1 * wl;
}

// intra-wave LDS ordering fence: HW DS ops are in-order per wave; this stops
// compiler reordering and drains lgkm. No inter-wave coupling (act is
// wave-private; blob is read-only after the single __syncthreads in prep).
__device__ __forceinline__ void wavesync() {
    asm volatile("s_waitcnt lgkmcnt(0)" ::: "memory");
    __builtin_amdgcn_sched_barrier(0);
}

// ============ MFMA layer: weights from LDS blob (hi/lo), 16-pt tile ============
template <int NKT, bool SHT>
__device__ __forceinline__ void mfma_layer_lds(const u32* blob, const u32* actw,
                                               int lane, f32x4 acc[4]) {
    const int q = lane >> 4, r = lane & 15;
    const int half = NKT * 1024;
    #pragma unroll
    for (int it = 0; it < 4; it++) acc[it] = (f32x4){0.f, 0.f, 0.f, 0.f};
    #pragma unroll
    for (int kt = 0; kt < NKT; kt++) {
        f16x8 whi[4], wlo[4];
        #pragma unroll
        for (int it = 0; it < 4; it++) {
            const u32* pb = blob + ((it * NKT + kt) * 64 + lane) * 4;
            const u32* pl = pb + half;
            whi[it] = cast8h(pb[0], pb[1], pb[2], pb[3]);
            wlo[it] = cast8h(pl[0], pl[1], pl[2], pl[3]);
        }
        bool zero = SHT && (kt == NKT - 1) && (q >= 2);
        const u32* rowp = actw + r * STR + kt * 32 + q * 8;
        u32 v[8];
        #pragma unroll
        for (int e = 0; e < 8; e++) v[e] = zero ? 0u : rowp[e];
        u32 xh[4], xl[4];
        #pragma unroll
        for (int j2 = 0; j2 < 4; j2++) {
            xh[j2] = (v[2*j2] >> 16) | (v[2*j2+1] & 0xffff0000u);
            xl[j2] = (v[2*j2] & 0xffffu) | (v[2*j2+1] << 16);
        }
        f16x8 bh = cast8h(xh[0], xh[1], xh[2], xh[3]);
        f16x8 bl = cast8h(xl[0], xl[1], xl[2], xl[3]);
        #pragma unroll
        for (int it = 0; it < 4; it++) {
            acc[it] = __builtin_amdgcn_mfma_f32_16x16x32_f16(whi[it], bh, acc[it], 0, 0, 0);
            acc[it] = __builtin_amdgcn_mfma_f32_16x16x32_f16(whi[it], bl, acc[it], 0, 0, 0);
            acc[it] = __builtin_amdgcn_mfma_f32_16x16x32_f16(wlo[it], bh, acc[it], 0, 0, 0);
        }
    }
}

__device__ __forceinline__ void epilogue_gelu(f32x4 acc[4], const float* __restrict__ bias,
                                              u32* actw, int lane) {
    const int q = lane >> 4, r = lane & 15;
    #pragma unroll
    for (int it = 0; it < 4; it++) {
        int mb = it * 16 + q * 4;
        float c0 = bias[mb], c1 = bias[mb + 1], c2 = bias[mb + 2], c3 = bias[mb + 3];
        f32x4 d = acc[it];
        u32* dst = actw + r * STR + mb;
        // descale 2^-16 (A,B both x256), gelu, re-scale 2^8 for the next layer
        dst[0] = packhl(gelu_f(fmaf(d[0], 0x1p-16f, c0)) * 256.0f);
        dst[1] = packhl(gelu_f(fmaf(d[1], 0x1p-16f, c1)) * 256.0f);
        dst[2] = packhl(gelu_f(fmaf(d[2], 0x1p-16f, c2)) * 256.0f);
        dst[3] = packhl(gelu_f(fmaf(d[3], 0x1p-16f, c3)) * 256.0f);
    }
}

// ================= persistent kernel: prep weights once, loop over tiles =================
__global__ void __launch_bounds__(512, 2) nerf_persist(
    const float* __restrict__ pos, const float* __restrict__ dirs,
    const int* __restrict__ iter, const float* __restrict__ tables,
    const int* __restrict__ shifts,
    const float* __restrict__ W1, const float* __restrict__ b1,
    const float* __restrict__ W2, const float* __restrict__ b2,
    const float* __restrict__ W3, const float* __restrict__ b3,
    const float* __restrict__ W4, const float* __restrict__ b4,
    const float* __restrict__ R1, const float* __restrict__ rb1,
    const float* __restrict__ R2, const float* __restrict__ rb2,
    const float* __restrict__ R3, const float* __restrict__ rb3,
    float* __restrict__ out, int n, int nbat)
{
    extern __shared__ u32 lds[];
    const int tid  = threadIdx.x;
    const int lane = tid & 63;
    const int wave = tid >> 6;
    const int r = lane & 15;       // point slot within wave tile
    const int h = lane >> 4;       // quarter index 0..3 (== q)

    // ---- prep: convert all weights into the LDS blob (once per block) ----
    {
        const float* Wp[6] = { W1, W2, W3, W4, R1, R2 };
        for (int e2 = tid; e2 < 13312; e2 += 512) {
            int p = e2, base, nkt, Ksrc, ldm, coloff, layer;
            if      (p < 2048)  { layer=0; base=WB1;  nkt=2; Ksrc=51; ldm=64; coloff=0; }
            else if (p < 4096)  { layer=1; base=WB2;  nkt=2; Ksrc=64; ldm=64; coloff=0; p-=2048; }
            else if (p < 6144)  { layer=2; base=WB3;  nkt=2; Ksrc=64; ldm=64; coloff=0; p-=4096; }
            else if (p < 8192)  { layer=3; base=WB4;  nkt=2; Ksrc=64; ldm=65; coloff=1; p-=6144; }
            else if (p < 11264) { layer=4; base=WBR1; nkt=3; Ksrc=80; ldm=64; coloff=0; p-=8192; }
            else                { layer=5; base=WBR2; nkt=2; Ksrc=64; ldm=64; coloff=0; p-=11264; }
            const float* W = Wp[layer];
            int j = p & 3, ln = (p >> 2) & 63, fk = p >> 8;
            int qq = ln >> 4, rr = ln & 15;
            int kt = fk % nkt, it = fk / nkt;
            int m  = it * 16 + rr;
            int k0 = kt * 32 + qq * 8 + 2 * j;
            float w0 = (k0     < Ksrc) ? W[(size_t)k0 * ldm + m + coloff] * 256.0f : 0.0f;
            float w1 = (k0 + 1 < Ksrc) ? W[(size_t)(k0 + 1) * ldm + m + coloff] * 256.0f : 0.0f;
            u16 h0, l0, h1, l1; hsplit(w0, h0, l0); hsplit(w1, h1, l1);
            int half = nkt * 1024;
            int idx  = base + (fk * 64 + ln) * 4 + j;
            lds[idx]        = (u32)h0 | ((u32)h1 << 16);
            lds[idx + half] = (u32)l0 | ((u32)l1 << 16);
        }
        if (tid < 24) {
            float sc, wl; window_scale(tid, iter, sc, wl);
            lds[SWOFF + 2*tid]     = __float_as_uint(sc);
            lds[SWOFF + 2*tid + 1] = __float_as_uint(wl);
        }
        if (tid >= 64 && tid < 128)  lds[W4C + tid - 64]  = __float_as_uint(W4[(size_t)(tid - 64) * 65]);
        if (tid >= 128 && tid < 320) lds[R3C + tid - 128] = __float_as_uint(R3[tid - 128]);
        if (tid >= 320 && tid < 392) lds[SHF + tid - 320] = (u32)shifts[tid - 320];
    }
    __syncthreads();   // blob/tables ready; read-only hereafter

    u32* actw  = lds + ACT0 + wave * ACTSZ;
    u32* myrow = actw + r * STR;

    for (int bb = blockIdx.x; bb < nbat; bb += gridDim.x) {
        const int tile = bb * WAVES + wave;
        const bool tok = ((size_t)tile * TPW < (size_t)n);
        const int i    = tile * TPW + r;
        const bool valid = tok && (i < n);

        float px = 0.f, py = 0.f, pz = 0.f;
        if (valid) { px = pos[3*i]; py = pos[3*i+1]; pz = pos[3*i+2]; }

        // ---- encode: 4 lanes per point, 6 levels each ----
        if (tok) {
            if (h == 0) {
                #pragma unroll
                for (int k = 51; k < 64; k++) myrow[k] = 0u;
                myrow[48] = packhl(px * 256.0f);
                myrow[49] = packhl(py * 256.0f);
                myrow[50] = packhl(pz * 256.0f);
            }
            #pragma unroll 3
            for (int li = 0; li < 6; li++) {
                int l = h * 6 + li;
                float sc = __uint_as_float(lds[SWOFF + 2*l]);
                float wl = __uint_as_float(lds[SWOFF + 2*l + 1]);
                int sx = (int)lds[SHF + 3*l], sy = (int)lds[SHF + 3*l + 1], sz = (int)lds[SHF + 3*l + 2];
                float f0, f1;
                hash_level(px, py, pz, sc, wl, sx, sy, sz,
                           tables + 2 * ((size_t)l * CAPN), f0, f1);
                myrow[2*l]     = (u32)f2h(f0 * 256.0f) << 16;
                myrow[2*l + 1] = (u32)f2h(f1 * 256.0f) << 16;
            }
        }
        wavesync();

        f32x4 acc[4];
        if (tok) { mfma_layer_lds<2, false>(lds + WB1, actw, lane, acc); epilogue_gelu(acc, b1, actw, lane); }
        wavesync();
        if (tok) { mfma_layer_lds<2, false>(lds + WB2, actw, lane, acc); epilogue_gelu(acc, b2, actw, lane); }
        wavesync();
        if (tok) { mfma_layer_lds<2, false>(lds + WB3, actw, lane, acc); epilogue_gelu(acc, b3, actw, lane); }
        wavesync();

        if (tok) {
            // density: k-split across quarters, combine via shfl_xor(16,32)
            float t = 0.f;
            #pragma unroll
            for (int kk = 0; kk < 16; kk++) {
                int k = h * 16 + kk;
                t = fmaf(unpackhl(myrow[k]), __uint_as_float(lds[W4C + k]), t);
            }
            t += __shfl_xor(t, 16);
            t += __shfl_xor(t, 32);
            float s = fmaf(t, 0x1p-8f, b4[0]);
            if (h == 0 && valid) out[(size_t)3 * n + i] = fmaxf(s, 0.f) + log1pf(expf(-fabsf(s)));

            mfma_layer_lds<2, false>(lds + WB4, actw, lane, acc);   // W4 cols 1..64
            epilogue_gelu(acc, b4 + 1, actw, lane);

            // SH -> feats 64..79 (stored x256); each quarter writes 4 cols
            float dx = 0.f, dy = 0.f, dz = 0.f;
            if (valid) { dx = dirs[3*i]; dy = dirs[3*i+1]; dz = dirs[3*i+2]; }
            float xx = dx*dx, yy = dy*dy, zz = dz*dz;
            float sh[16];
            sh[0]  = 0.28209479177387814f;
            sh[1]  = -0.48860251190291987f * dy;
            sh[2]  = 0.48860251190291987f * dz;
            sh[3]  = -0.48860251190291987f * dx;
            sh[4]  = 1.0925484305920792f * dx * dy;
            sh[5]  = -1.0925484305920792f * dy * dz;
            sh[6]  = 0.94617469575756f * zz - 0.31539156525252f;
            sh[7]  = -1.0925484305920792f * dx * dz;
            sh[8]  = 0.5462742152960396f * (xx - yy);
            sh[9]  = -0.5900435899266435f * dy * (3.0f * xx - yy);
            sh[10] = 2.890611442640554f * dx * dy * dz;
            sh[11] = -0.4570457994644657f * dy * (4.0f * zz - xx - yy);
            sh[12] = 0.37317633259011546f * dz * (2.0f * zz - 3.0f * xx - 3.0f * yy);
            sh[13] = -0.4570457994644657f * dx * (4.0f * zz - xx - yy);
            sh[14] = 1.445305721320277f * dz * (xx - yy);
            sh[15] = -0.5900435899266435f * dx * (xx - 3.0f * yy);
            #pragma unroll
            for (int j = 0; j < 4; j++) myrow[64 + h * 4 + j] = packhl(sh[h * 4 + j] * 256.0f);
        }
        wavesync();

        if (tok) { mfma_layer_lds<3, true >(lds + WBR1, actw, lane, acc); epilogue_gelu(acc, rb1, actw, lane); }
        wavesync();
        if (tok) { mfma_layer_lds<2, false>(lds + WBR2, actw, lane, acc); epilogue_gelu(acc, rb2, actw, lane); }
        wavesync();

        if (tok) {
            // R3 + sigmoid: k-split across quarters
            float t0 = 0.f, t1 = 0.f, t2 = 0.f;
            #pragma unroll
            for (int kk = 0; kk < 16; kk++) {
                int k = h * 16 + kk;
                float xv = unpackhl(myrow[k]);
                t0 = fmaf(xv, __uint_as_float(lds[R3C + 3*k + 0]), t0);
                t1 = fmaf(xv, __uint_as_float(lds[R3C + 3*k + 1]), t1);
                t2 = fmaf(xv, __uint_as_float(lds[R3C + 3*k + 2]), t2);
            }
            t0 += __shfl_xor(t0, 16); t0 += __shfl_xor(t0, 32);
            t1 += __shfl_xor(t1, 16); t1 += __shfl_xor(t1, 32);
            t2 += __shfl_xor(t2, 16); t2 += __shfl_xor(t2, 32);
            if (h == 0 && valid) {
                float y0 = fmaf(t0, 0x1p-8f, rb3[0]);
                float y1 = fmaf(t1, 0x1p-8f, rb3[1]);
                float y2 = fmaf(t2, 0x1p-8f, rb3[2]);
                out[(size_t)3 * i + 0] = sigmoid_f(y0);
                out[(size_t)3 * i + 1] = sigmoid_f(y1);
                out[(size_t)3 * i + 2] = sigmoid_f(y2);
            }
        }
        wavesync();
    }
}

extern "C" void kernel_launch(void* const* d_in, const int* in_sizes, int n_in,
                              void* d_out, int out_size, void* d_ws, size_t ws_size,
                              hipStream_t stream) {
    (void)d_ws; (void)ws_size;
    int n = in_sizes[0] / 3;
    int ntiles = (n + TPW - 1) / TPW;
    int nbat = (ntiles + WAVES - 1) / WAVES;
    int grid = nbat < 256 ? nbat : 256;
    size_t ldsb = (size_t)LDS_U32 * 4;   // 150016 B

    hipFuncSetAttribute(reinterpret_cast<const void*>(nerf_persist),
                        hipFuncAttributeMaxDynamicSharedMemorySize, (int)ldsb);

    nerf_persist<<<grid, 512, ldsb, stream>>>(
        (const float*)d_in[0], (const float*)d_in[1], (const int*)d_in[2],
        (const float*)d_in[3], (const int*)d_in[4],
        (const float*)d_in[5],  (const float*)d_in[6],
        (const float*)d_in[7],  (const float*)d_in[8],
        (const float*)d_in[9],  (const float*)d_in[10],
        (const float*)d_in[11], (const float*)d_in[12],
        (const float*)d_in[13], (const float*)d_in[14],
        (const float*)d_in[15], (const float*)d_in[16],
        (const float*)d_in[17], (const float*)d_in[18],
        (float*)d_out, n, nbat);
}

// Round 6
// 1337.015 us; speedup vs baseline: 1.3732x; 1.0616x over previous
//
#include <hip/hip_runtime.h>
#include <math.h>

typedef unsigned short u16;
typedef unsigned int   u32;

#define LVLS 24
#define CAPN (1 << 18)
#define STR  84            // act row stride in u32: 84*4=336B = 21*16 -> every row 16B-aligned
#define WAVES 8            // waves per block (512 threads)
#define TPW  16            // points per wave tile
#define ACTSZ (TPW * STR + 16)   // 1360 u32 per wave act slice (+pad for R1 q>=2 reads)

// ---- LDS layout (u32 offsets) ----
#define WB1   0
#define WB2   4096
#define WB3   8192
#define WB4   12288        /* W4 cols 1..64 */
#define WBR1  16384        /* NKT=3 */
#define WBR2  22528        /* blob end 26624 */
#define SWOFF 26624        /* 24 x {scale, window} floats  -> 48 u32 */
#define W4C   26672        /* W4 column 0 (64 floats) */
#define R3C   26736        /* R3 64x3 floats (192) */
#define SHF   26928        /* shifts 24x3 ints (72) */
#define ACT0  27008        /* 8 wave act slices of ACTSZ */
#define LDS_U32 (ACT0 + WAVES * ACTSZ)   /* 37888 u32 = 151552 B <= 160 KiB */

typedef float    f32x4 __attribute__((ext_vector_type(4)));
typedef _Float16 f16x8 __attribute__((ext_vector_type(8)));
typedef u32      u32x4 __attribute__((ext_vector_type(4)));

#if __has_builtin(__builtin_amdgcn_rcpf)
#define RCPF(x) __builtin_amdgcn_rcpf(x)
#else
#define RCPF(x) (1.0f / (x))
#endif
#if __has_builtin(__builtin_amdgcn_exp2f)
#define EXP2F(x) __builtin_amdgcn_exp2f(x)
#else
#define EXP2F(x) exp2f(x)
#endif

// ---- global scaling scheme (fp16-denormal avoidance; verified abs=3.9e-3) ----
// B side (activations / pos / SH / hash feats) stored as 256*x in fp16 hi/lo.
// A side (weights) converted once per block to 256*w hi/lo blob in LDS.
// MFMA acc = 65536 * (x.w); epilogue descales via fmaf(d, 2^-16, bias).
// SELF-CONTAINED: reads ONLY d_in, writes ONLY d_out (no d_ws -> replay-safe).
//
// r6 fixes (from r5 counters):
//  - encode is LEVEL-LOCKSTEP: whole wave on one level at a time (4 lanes/point
//    x 2 corners, shfl_xor reduce). r5's 4-way level split thrashed L2
//    (FETCH 1.83->4.09 GB across r3/r4/r5 as level-parallelism grew).
//  - all LDS traffic vectorized to b128 (u32x4); r5's scalar blob reads were
//    8-way bank conflicts (SQ_LDS_BANK_CONFLICT x7.5). STR 81->84 for 16B align.

__device__ __forceinline__ float h2f(u16 b) {
    union { u16 u; _Float16 h; } v; v.u = b; return (float)v.h;
}
__device__ __forceinline__ u16 f2h(float x) {
    union { _Float16 h; u16 u; } v; v.h = (_Float16)x; return v.u;   // RNE v_cvt_f16_f32
}
__device__ __forceinline__ void hsplit(float x, u16& h, u16& l) {
    h = f2h(x);
    float r = x - h2f(h);
    l = f2h(r);
}
__device__ __forceinline__ u32 packhl(float x) {
    u16 h, l; hsplit(x, h, l);
    return ((u32)h << 16) | l;
}
__device__ __forceinline__ float unpackhl(u32 w) {
    return h2f((u16)(w >> 16)) + h2f((u16)(w & 0xffffu));
}
// A&S 7.1.26 erf (|eps|<=1.5e-7), hw rcp + exp2
__device__ __forceinline__ float gelu_f(float x) {
    float z  = fabsf(x) * 0.70710678118654752f;
    float t  = RCPF(fmaf(0.3275911f, z, 1.0f));
    float e  = EXP2F(-z * z * 1.44269504088896340f);
    float p  = fmaf(1.061405429f, t, -1.453152027f);
    p = fmaf(p, t, 1.421413741f);
    p = fmaf(p, t, -0.284496736f);
    p = fmaf(p, t, 0.254829592f);
    p = p * t;
    float erfv = fmaf(-p, e, 1.0f);
    float se   = copysignf(erfv, x);
    return x * fmaf(0.5f, se, 0.5f);
}
__device__ __forceinline__ float sigmoid_f(float y) {
    return RCPF(1.0f + EXP2F(-y * 1.44269504088896340f));
}
__device__ __forceinline__ f16x8 cast8h(u32 a, u32 b, u32 c, u32 d) {
    union { u32 u[4]; f16x8 h; } v; v.u[0]=a; v.u[1]=b; v.u[2]=c; v.u[3]=d; return v.h;
}
__device__ __forceinline__ f16x8 cast8hv(u32x4 u) {
    union { u32x4 u4; f16x8 h; } v; v.u4 = u; return v.h;
}
__device__ __forceinline__ void window_scale(int l, const int* iter, float& sc, float& wl) {
    sc = powf(10.0f, (float)l * (-4.0f / 23.0f));
    double itd = (double)iter[0] / 10000.0;
    itd = itd < 0.0 ? 0.0 : (itd > 1.0 ? 1.0 : itd);
    float tL = (float)((0.3 + 0.7 * itd) * 24.0);
    float arg = fminf(fmaxf(tL - (float)l, 0.0f), 1.0f);
    wl = 0.5f - 0.5f * cosf(3.14159265358979323846f * arg);
}

// corner-parallel partial: this lane handles corners c0, c0+1 of one level
__device__ __forceinline__ void hash_level_part(float px, float py, float pz, float sc,
                                                int sx, int sy, int sz, int c0,
                                                const float* __restrict__ tl,
                                                float2& g0, float2& g1, float& w0, float& w1) {
    float cx = px / sc, cy = py / sc, cz = pz / sc;
    float fx = floorf(cx), fy = floorf(cy), fz = floorf(cz);
    float rx = cx - fx, ry = cy - fy, rz = cz - fz;
    int bx = (int)fx + sx, by = (int)fy + sy, bz = (int)fz + sz;
    #pragma unroll
    for (int cc = 0; cc < 2; cc++) {
        int c = c0 + cc;
        u32 hx = (u32)(bx + (c & 1));
        u32 hy = (u32)(by + ((c >> 1) & 1)) * 2654435761u;
        u32 hz = (u32)(bz + ((c >> 2) & 1)) * 805459861u;
        u32 idx = (hx ^ hy ^ hz) & (CAPN - 1);
        float w = ((c & 1) ? rx : 1.0f - rx)
                * ((c & 2) ? ry : 1.0f - ry)
                * ((c & 4) ? rz : 1.0f - rz);
        float2 tf = *(const float2*)(tl + 2 * (size_t)idx);
        if (cc == 0) { g0 = tf; w0 = w; } else { g1 = tf; w1 = w; }
    }
}

// intra-wave LDS ordering fence (act slices are wave-private)
__device__ __forceinline__ void wavesync() {
    asm volatile("s_waitcnt lgkmcnt(0)" ::: "memory");
    __builtin_amdgcn_sched_barrier(0);
}

// ============ MFMA layer: weights from LDS blob (hi/lo), 16-pt tile ============
template <int NKT, bool SHT>
__device__ __forceinline__ void mfma_layer_lds(const u32* blob, const u32* actw,
                                               int lane, f32x4 acc[4]) {
    const int q = lane >> 4, r = lane & 15;
    const int half = NKT * 1024;
    #pragma unroll
    for (int it = 0; it < 4; it++) acc[it] = (f32x4){0.f, 0.f, 0.f, 0.f};
    #pragma unroll
    for (int kt = 0; kt < NKT; kt++) {
        f16x8 whi[4], wlo[4];
        #pragma unroll
        for (int it = 0; it < 4; it++) {
            const u32* pb = blob + ((it * NKT + kt) * 64 + lane) * 4;
            u32x4 hv = *(const u32x4*)pb;            // ds_read_b128, dense
            u32x4 lv = *(const u32x4*)(pb + half);
            whi[it] = cast8hv(hv);
            wlo[it] = cast8hv(lv);
        }
        bool zero = SHT && (kt == NKT - 1) && (q >= 2);
        const u32* rowp = actw + r * STR + kt * 32 + q * 8;
        u32x4 v0 = *(const u32x4*)rowp;              // 16B-aligned (STR=84)
        u32x4 v1 = *(const u32x4*)(rowp + 4);
        if (zero) { v0 = (u32x4){0,0,0,0}; v1 = (u32x4){0,0,0,0}; }
        u32 v[8] = { v0.x, v0.y, v0.z, v0.w, v1.x, v1.y, v1.z, v1.w };
        u32 xh[4], xl[4];
        #pragma unroll
        for (int j2 = 0; j2 < 4; j2++) {
            xh[j2] = (v[2*j2] >> 16) | (v[2*j2+1] & 0xffff0000u);
            xl[j2] = (v[2*j2] & 0xffffu) | (v[2*j2+1] << 16);
        }
        f16x8 bh = cast8h(xh[0], xh[1], xh[2], xh[3]);
        f16x8 bl = cast8h(xl[0], xl[1], xl[2], xl[3]);
        #pragma unroll
        for (int it = 0; it < 4; it++) {
            acc[it] = __builtin_amdgcn_mfma_f32_16x16x32_f16(whi[it], bh, acc[it], 0, 0, 0);
            acc[it] = __builtin_amdgcn_mfma_f32_16x16x32_f16(whi[it], bl, acc[it], 0, 0, 0);
            acc[it] = __builtin_amdgcn_mfma_f32_16x16x32_f16(wlo[it], bh, acc[it], 0, 0, 0);
        }
    }
}

__device__ __forceinline__ void epilogue_gelu(f32x4 acc[4], const float* __restrict__ bias,
                                              u32* actw, int lane) {
    const int q = lane >> 4, r = lane & 15;
    #pragma unroll
    for (int it = 0; it < 4; it++) {
        int mb = it * 16 + q * 4;
        float c0 = bias[mb], c1 = bias[mb + 1], c2 = bias[mb + 2], c3 = bias[mb + 3];
        f32x4 d = acc[it];
        u32x4 wv;
        // descale 2^-16 (A,B both x256), gelu, re-scale 2^8 for the next layer
        wv.x = packhl(gelu_f(fmaf(d[0], 0x1p-16f, c0)) * 256.0f);
        wv.y = packhl(gelu_f(fmaf(d[1], 0x1p-16f, c1)) * 256.0f);
        wv.z = packhl(gelu_f(fmaf(d[2], 0x1p-16f, c2)) * 256.0f);
        wv.w = packhl(gelu_f(fmaf(d[3], 0x1p-16f, c3)) * 256.0f);
        *(u32x4*)(actw + r * STR + mb) = wv;         // ds_write_b128
    }
}

// ================= persistent kernel: prep weights once, loop over tiles =================
__global__ void __launch_bounds__(512, 2) nerf_persist(
    const float* __restrict__ pos, const float* __restrict__ dirs,
    const int* __restrict__ iter, const float* __restrict__ tables,
    const int* __restrict__ shifts,
    const float* __restrict__ W1, const float* __restrict__ b1,
    const float* __restrict__ W2, const float* __restrict__ b2,
    const float* __restrict__ W3, const float* __restrict__ b3,
    const float* __restrict__ W4, const float* __restrict__ b4,
    const float* __restrict__ R1, const float* __restrict__ rb1,
    const float* __restrict__ R2, const float* __restrict__ rb2,
    const float* __restrict__ R3, const float* __restrict__ rb3,
    float* __restrict__ out, int n, int nbat)
{
    extern __shared__ u32 lds[];
    const int tid  = threadIdx.x;
    const int lane = tid & 63;
    const int wave = tid >> 6;
    const int r = lane & 15;       // point slot within wave tile
    const int h = lane >> 4;       // quarter index 0..3 (== q)

    // ---- prep: convert all weights into the LDS blob (once per block) ----
    {
        const float* Wp[6] = { W1, W2, W3, W4, R1, R2 };
        for (int e2 = tid; e2 < 13312; e2 += 512) {
            int p = e2, base, nkt, Ksrc, ldm, coloff, layer;
            if      (p < 2048)  { layer=0; base=WB1;  nkt=2; Ksrc=51; ldm=64; coloff=0; }
            else if (p < 4096)  { layer=1; base=WB2;  nkt=2; Ksrc=64; ldm=64; coloff=0; p-=2048; }
            else if (p < 6144)  { layer=2; base=WB3;  nkt=2; Ksrc=64; ldm=64; coloff=0; p-=4096; }
            else if (p < 8192)  { layer=3; base=WB4;  nkt=2; Ksrc=64; ldm=65; coloff=1; p-=6144; }
            else if (p < 11264) { layer=4; base=WBR1; nkt=3; Ksrc=80; ldm=64; coloff=0; p-=8192; }
            else                { layer=5; base=WBR2; nkt=2; Ksrc=64; ldm=64; coloff=0; p-=11264; }
            const float* W = Wp[layer];
            int j = p & 3, ln = (p >> 2) & 63, fk = p >> 8;
            int qq = ln >> 4, rr = ln & 15;
            int kt = fk % nkt, it = fk / nkt;
            int m  = it * 16 + rr;
            int k0 = kt * 32 + qq * 8 + 2 * j;
            float w0 = (k0     < Ksrc) ? W[(size_t)k0 * ldm + m + coloff] * 256.0f : 0.0f;
            float w1 = (k0 + 1 < Ksrc) ? W[(size_t)(k0 + 1) * ldm + m + coloff] * 256.0f : 0.0f;
            u16 h0, l0, h1, l1; hsplit(w0, h0, l0); hsplit(w1, h1, l1);
            int half = nkt * 1024;
            int idx  = base + (fk * 64 + ln) * 4 + j;
            lds[idx]        = (u32)h0 | ((u32)h1 << 16);
            lds[idx + half] = (u32)l0 | ((u32)l1 << 16);
        }
        if (tid < 24) {
            float sc, wl; window_scale(tid, iter, sc, wl);
            lds[SWOFF + 2*tid]     = __float_as_uint(sc);
            lds[SWOFF + 2*tid + 1] = __float_as_uint(wl);
        }
        if (tid >= 64 && tid < 128)  lds[W4C + tid - 64]  = __float_as_uint(W4[(size_t)(tid - 64) * 65]);
        if (tid >= 128 && tid < 320) lds[R3C + tid - 128] = __float_as_uint(R3[tid - 128]);
        if (tid >= 320 && tid < 392) lds[SHF + tid - 320] = (u32)shifts[tid - 320];
    }
    __syncthreads();   // blob/tables ready; read-only hereafter

    u32* actw  = lds + ACT0 + wave * ACTSZ;
    u32* myrow = actw + r * STR;

    for (int bb = blockIdx.x; bb < nbat; bb += gridDim.x) {
        const int tile = bb * WAVES + wave;
        const bool tok = ((size_t)tile * TPW < (size_t)n);
        const int i    = tile * TPW + r;
        const bool valid = tok && (i < n);

        float px = 0.f, py = 0.f, pz = 0.f;
        if (valid) { px = pos[3*i]; py = pos[3*i+1]; pz = pos[3*i+2]; }

        // ---- encode: LEVEL-LOCKSTEP, 4 lanes/point x 2 corners, shfl reduce ----
        if (tok) {
            if (h == 0) {
                #pragma unroll
                for (int k = 51; k < 64; k++) myrow[k] = 0u;
                myrow[48] = packhl(px * 256.0f);
                myrow[49] = packhl(py * 256.0f);
                myrow[50] = packhl(pz * 256.0f);
            }
            const int c0 = h * 2;
            #pragma unroll 2
            for (int l = 0; l < LVLS; l++) {
                float sc = __uint_as_float(lds[SWOFF + 2*l]);
                float wl = __uint_as_float(lds[SWOFF + 2*l + 1]);
                int sx = (int)lds[SHF + 3*l], sy = (int)lds[SHF + 3*l + 1], sz = (int)lds[SHF + 3*l + 2];
                float2 g0, g1; float w0, w1;
                hash_level_part(px, py, pz, sc, sx, sy, sz, c0,
                                tables + 2 * ((size_t)l * CAPN), g0, g1, w0, w1);
                float a0 = fmaf(w0, g0.x, w1 * g1.x);
                float a1 = fmaf(w0, g0.y, w1 * g1.y);
                a0 += __shfl_xor(a0, 16); a0 += __shfl_xor(a0, 32);
                a1 += __shfl_xor(a1, 16); a1 += __shfl_xor(a1, 32);
                if (h == 0) {
                    myrow[2*l]     = (u32)f2h(a0 * wl * 256.0f) << 16;
                    myrow[2*l + 1] = (u32)f2h(a1 * wl * 256.0f) << 16;
                }
            }
        }
        wavesync();

        f32x4 acc[4];
        if (tok) { mfma_layer_lds<2, false>(lds + WB1, actw, lane, acc); epilogue_gelu(acc, b1, actw, lane); }
        wavesync();
        if (tok) { mfma_layer_lds<2, false>(lds + WB2, actw, lane, acc); epilogue_gelu(acc, b2, actw, lane); }
        wavesync();
        if (tok) { mfma_layer_lds<2, false>(lds + WB3, actw, lane, acc); epilogue_gelu(acc, b3, actw, lane); }
        wavesync();

        if (tok) {
            // density: k-split across quarters, combine via shfl_xor(16,32)
            float t = 0.f;
            #pragma unroll
            for (int kk = 0; kk < 16; kk++) {
                int k = h * 16 + kk;
                t = fmaf(unpackhl(myrow[k]), __uint_as_float(lds[W4C + k]), t);
            }
            t += __shfl_xor(t, 16);
            t += __shfl_xor(t, 32);
            float s = fmaf(t, 0x1p-8f, b4[0]);
            if (h == 0 && valid) out[(size_t)3 * n + i] = fmaxf(s, 0.f) + log1pf(expf(-fabsf(s)));

            mfma_layer_lds<2, false>(lds + WB4, actw, lane, acc);   // W4 cols 1..64
            epilogue_gelu(acc, b4 + 1, actw, lane);

            // SH -> feats 64..79 (stored x256); each quarter writes 4 cols
            float dx = 0.f, dy = 0.f, dz = 0.f;
            if (valid) { dx = dirs[3*i]; dy = dirs[3*i+1]; dz = dirs[3*i+2]; }
            float xx = dx*dx, yy = dy*dy, zz = dz*dz;
            float sh[16];
            sh[0]  = 0.28209479177387814f;
            sh[1]  = -0.48860251190291987f * dy;
            sh[2]  = 0.48860251190291987f * dz;
            sh[3]  = -0.48860251190291987f * dx;
            sh[4]  = 1.0925484305920792f * dx * dy;
            sh[5]  = -1.0925484305920792f * dy * dz;
            sh[6]  = 0.94617469575756f * zz - 0.31539156525252f;
            sh[7]  = -1.0925484305920792f * dx * dz;
            sh[8]  = 0.5462742152960396f * (xx - yy);
            sh[9]  = -0.5900435899266435f * dy * (3.0f * xx - yy);
            sh[10] = 2.890611442640554f * dx * dy * dz;
            sh[11] = -0.4570457994644657f * dy * (4.0f * zz - xx - yy);
            sh[12] = 0.37317633259011546f * dz * (2.0f * zz - 3.0f * xx - 3.0f * yy);
            sh[13] = -0.4570457994644657f * dx * (4.0f * zz - xx - yy);
            sh[14] = 1.445305721320277f * dz * (xx - yy);
            sh[15] = -0.5900435899266435f * dx * (xx - 3.0f * yy);
            #pragma unroll
            for (int j = 0; j < 4; j++) myrow[64 + h * 4 + j] = packhl(sh[h * 4 + j] * 256.0f);
        }
        wavesync();

        if (tok) { mfma_layer_lds<3, true >(lds + WBR1, actw, lane, acc); epilogue_gelu(acc, rb1, actw, lane); }
        wavesync();
        if (tok) { mfma_layer_lds<2, false>(lds + WBR2, actw, lane, acc); epilogue_gelu(acc, rb2, actw, lane); }
        wavesync();

        if (tok) {
            // R3 + sigmoid: k-split across quarters
            float t0 = 0.f, t1 = 0.f, t2 = 0.f;
            #pragma unroll
            for (int kk = 0; kk < 16; kk++) {
                int k = h * 16 + kk;
                float xv = unpackhl(myrow[k]);
                t0 = fmaf(xv, __uint_as_float(lds[R3C + 3*k + 0]), t0);
                t1 = fmaf(xv, __uint_as_float(lds[R3C + 3*k + 1]), t1);
                t2 = fmaf(xv, __uint_as_float(lds[R3C + 3*k + 2]), t2);
            }
            t0 += __shfl_xor(t0, 16); t0 += __shfl_xor(t0, 32);
            t1 += __shfl_xor(t1, 16); t1 += __shfl_xor(t1, 32);
            t2 += __shfl_xor(t2, 16); t2 += __shfl_xor(t2, 32);
            if (h == 0 && valid) {
                float y0 = fmaf(t0, 0x1p-8f, rb3[0]);
                float y1 = fmaf(t1, 0x1p-8f, rb3[1]);
                float y2 = fmaf(t2, 0x1p-8f, rb3[2]);
                out[(size_t)3 * i + 0] = sigmoid_f(y0);
                out[(size_t)3 * i + 1] = sigmoid_f(y1);
                out[(size_t)3 * i + 2] = sigmoid_f(y2);
            }
        }
        wavesync();
    }
}

extern "C" void kernel_launch(void* const* d_in, const int* in_sizes, int n_in,
                              void* d_out, int out_size, void* d_ws, size_t ws_size,
                              hipStream_t stream) {
    (void)d_ws; (void)ws_size;
    int n = in_sizes[0] / 3;
    int ntiles = (n + TPW - 1) / TPW;
    int nbat = (ntiles + WAVES - 1) / WAVES;
    int grid = nbat < 256 ? nbat : 256;
    size_t ldsb = (size_t)LDS_U32 * 4;   // 151552 B

    hipFuncSetAttribute(reinterpret_cast<const void*>(nerf_persist),
                        hipFuncAttributeMaxDynamicSharedMemorySize, (int)ldsb);

    nerf_persist<<<grid, 512, ldsb, stream>>>(
        (const float*)d_in[0], (const float*)d_in[1], (const int*)d_in[2],
        (const float*)d_in[3], (const int*)d_in[4],
        (const float*)d_in[5],  (const float*)d_in[6],
        (const float*)d_in[7],  (const float*)d_in[8],
        (const float*)d_in[9],  (const float*)d_in[10],
        (const float*)d_in[11], (const float*)d_in[12],
        (const float*)d_in[13], (const float*)d_in[14],
        (const float*)d_in[15], (const float*)d_in[16],
        (const float*)d_in[17], (const float*)d_in[18],
        (float*)d_out, n, nbat);
}